// Round 1
// baseline (9652.705 us; speedup 1.0000x reference)
//
#include <hip/hip_runtime.h>

#define N_IJKL   1000000
#define N_UIJK   500000
#define N_IJK    250000
#define N_UIJKL  2000000
#define LVL_STRIDE 4000000LL   // N_UIJK * 8 floats per level

// ---------------- tall-skinny GEMM: A[N,128] @ W[128,8] -> out[N,8] ----------------
__global__ __launch_bounds__(256) void k_gemm128x8(const float* __restrict__ A,
                                                   const float* __restrict__ W,
                                                   float* __restrict__ out) {
  __shared__ float sA[32][132];   // pad 132: bank spread + float4 alignment (528B rows)
  __shared__ float sW[8][132];    // W transposed: sW[h][c]
  const int t = threadIdx.x;
  for (int i = t; i < 1024; i += 256) sW[i & 7][i >> 3] = W[i];  // W[c*8+h] = W[i]
  const long long r0 = (long long)blockIdx.x * 32;
  const float4* A4 = (const float4*)(A + r0 * 128);
  for (int i = t; i < 1024; i += 256) {
    float4 v = A4[i];
    ((float4*)&sA[i >> 5][0])[i & 31] = v;
  }
  __syncthreads();
  const int row = t >> 3, h = t & 7;
  float acc = 0.f;
  #pragma unroll
  for (int c4 = 0; c4 < 32; ++c4) {
    float4 a = ((const float4*)&sA[row][0])[c4];
    float4 w = ((const float4*)&sW[h][0])[c4];
    acc = fmaf(a.x, w.x, acc); acc = fmaf(a.y, w.y, acc);
    acc = fmaf(a.z, w.z, acc); acc = fmaf(a.w, w.w, acc);
  }
  out[(r0 + row) * 8 + h] = acc;
}

// order-preserving f32 -> u32 map for atomicMax
__device__ __forceinline__ unsigned flip_f32(float x) {
  unsigned u = __float_as_uint(x);
  return (u & 0x80000000u) ? ~u : (u | 0x80000000u);
}
__device__ __forceinline__ float unflip_f32(unsigned u) {
  return __uint_as_float((u & 0x80000000u) ? (u & 0x7FFFFFFFu) : ~u);
}

// ---------------- segment max (atomic, flipped-uint) ----------------
__global__ __launch_bounds__(256) void k_segmax(const float* __restrict__ tpk,
                                                const int* __restrict__ seg,
                                                unsigned* __restrict__ mu) {
  int i = blockIdx.x * 256 + threadIdx.x;
  if (i >= N_IJKL) return;
  int sg = seg[i];
  const float4* r = (const float4*)(tpk + (long long)i * 8);
  float4 a = r[0], b = r[1];
  float v[8] = {a.x, a.y, a.z, a.w, b.x, b.y, b.z, b.w};
  unsigned* m = mu + (long long)sg * 8;
  #pragma unroll
  for (int h = 0; h < 8; ++h) atomicMax(&m[h], flip_f32(v[h]));
}

// ---------------- e = exp(tpk - m[seg]); s[seg] += e ----------------
__global__ __launch_bounds__(256) void k_expsum(float* __restrict__ tpk,
                                                const int* __restrict__ seg,
                                                const unsigned* __restrict__ mu,
                                                float* __restrict__ s) {
  int i = blockIdx.x * 256 + threadIdx.x;
  if (i >= N_IJKL) return;
  int sg = seg[i];
  float4* r = (float4*)(tpk + (long long)i * 8);
  float4 a = r[0], b = r[1];
  const unsigned* m = mu + (long long)sg * 8;
  float v[8] = {a.x, a.y, a.z, a.w, b.x, b.y, b.z, b.w};
  float e[8];
  float* sp = s + (long long)sg * 8;
  #pragma unroll
  for (int h = 0; h < 8; ++h) {
    e[h] = expf(v[h] - unflip_f32(m[h]));
    atomicAdd(&sp[h], e[h]);
  }
  r[0] = make_float4(e[0], e[1], e[2], e[3]);
  r[1] = make_float4(e[4], e[5], e[6], e[7]);
}

// ---------------- alpha = e / s[seg] (in place) ----------------
__global__ __launch_bounds__(256) void k_div(float* __restrict__ tpk,
                                             const int* __restrict__ seg,
                                             const float* __restrict__ s) {
  int i = blockIdx.x * 256 + threadIdx.x;
  if (i >= N_IJKL) return;
  int sg = seg[i];
  float4* r = (float4*)(tpk + (long long)i * 8);
  const float4* sp = (const float4*)(s + (long long)sg * 8);
  float4 a = r[0], b = r[1];
  float4 s0 = sp[0], s1 = sp[1];
  a.x /= s0.x; a.y /= s0.y; a.z /= s0.z; a.w /= s0.w;
  b.x /= s1.x; b.y /= s1.y; b.z /= s1.z; b.w /= s1.w;
  r[0] = a; r[1] = b;
}

// ---------------- kernel_edge[e] = alpha[g[e]] ----------------
__global__ __launch_bounds__(256) void k_gather(const float* __restrict__ alpha,
                                                const int* __restrict__ g,
                                                float* __restrict__ ker) {
  int e = blockIdx.x * 256 + threadIdx.x;
  if (e >= N_UIJKL) return;
  long long src = (long long)g[e] * 8;
  const float4* a = (const float4*)(alpha + src);
  float4* o = (float4*)(ker + (long long)e * 8);
  o[0] = a[0]; o[1] = a[1];
}

// ---------------- conv: lout[dst] += ker[e] * lin[src] ----------------
__global__ __launch_bounds__(256) void k_conv(const float* __restrict__ ker,
                                              const int* __restrict__ src_idx,
                                              const int* __restrict__ dst_idx,
                                              const float* __restrict__ lin,
                                              float* __restrict__ lout) {
  int e = blockIdx.x * 256 + threadIdx.x;
  if (e >= N_UIJKL) return;
  int src = src_idx[e], dst = dst_idx[e];
  const float4* kr = (const float4*)(ker + (long long)e * 8);
  const float4* gr = (const float4*)(lin + (long long)src * 8);
  float4 k0 = kr[0], k1 = kr[1];
  float4 g0 = gr[0], g1 = gr[1];
  float* d = lout + (long long)dst * 8;
  atomicAdd(d + 0, k0.x * g0.x);
  atomicAdd(d + 1, k0.y * g0.y);
  atomicAdd(d + 2, k0.z * g0.z);
  atomicAdd(d + 3, k0.w * g0.w);
  atomicAdd(d + 4, k1.x * g1.x);
  atomicAdd(d + 5, k1.y * g1.y);
  atomicAdd(d + 6, k1.z * g1.z);
  atomicAdd(d + 7, k1.w * g1.w);
}

// ---------------- fused MLP (72->72 GELU ->128) + residual ----------------
__global__ __launch_bounds__(128) void k_mlp(const float* __restrict__ lvl,
                                             const float* __restrict__ prop,
                                             const float* __restrict__ W1,
                                             const float* __restrict__ b1,
                                             const float* __restrict__ W2,
                                             const float* __restrict__ b2,
                                             float* __restrict__ out) {
  long long r = (long long)blockIdx.x * 128 + threadIdx.x;
  if (r >= N_UIJK) return;
  float x[72];
  #pragma unroll
  for (int t = 0; t < 9; ++t) {
    const float4* p = (const float4*)(lvl + (long long)t * LVL_STRIDE + r * 8);
    float4 a = p[0], b = p[1];
    x[t * 8 + 0] = a.x; x[t * 8 + 1] = a.y; x[t * 8 + 2] = a.z; x[t * 8 + 3] = a.w;
    x[t * 8 + 4] = b.x; x[t * 8 + 5] = b.y; x[t * 8 + 6] = b.z; x[t * 8 + 7] = b.w;
  }
  float h[72];
  #pragma unroll
  for (int j = 0; j < 72; ++j) h[j] = b1[j];
  #pragma unroll
  for (int c = 0; c < 72; ++c) {
    float xv = x[c];
    #pragma unroll
    for (int j = 0; j < 72; ++j) h[j] = fmaf(xv, W1[c * 72 + j], h[j]);
  }
  #pragma unroll
  for (int j = 0; j < 72; ++j) {
    float v = h[j];
    h[j] = 0.5f * v * (1.0f + erff(v * 0.70710678118654752f));  // exact GELU
  }
  const float4* pr = (const float4*)(prop + r * 128);
  float4* po = (float4*)(out + r * 128);
  #pragma unroll
  for (int kc = 0; kc < 2; ++kc) {
    float o[64];
    #pragma unroll
    for (int k = 0; k < 64; ++k) o[k] = b2[kc * 64 + k];
    #pragma unroll
    for (int j = 0; j < 72; ++j) {
      float hv = h[j];
      #pragma unroll
      for (int k = 0; k < 64; ++k) o[k] = fmaf(hv, W2[j * 128 + kc * 64 + k], o[k]);
    }
    #pragma unroll
    for (int k4 = 0; k4 < 16; ++k4) {
      float4 pv = pr[kc * 16 + k4];
      float4 ov;
      ov.x = o[k4 * 4 + 0] + pv.x;
      ov.y = o[k4 * 4 + 1] + pv.y;
      ov.z = o[k4 * 4 + 2] + pv.z;
      ov.w = o[k4 * 4 + 3] + pv.w;
      po[kc * 16 + k4] = ov;
    }
  }
}

extern "C" void kernel_launch(void* const* d_in, const int* in_sizes, int n_in,
                              void* d_out, int out_size, void* d_ws, size_t ws_size,
                              hipStream_t stream) {
  const float* prop   = (const float*)d_in[0];
  const float* stereo = (const float*)d_in[1];
  const float* Wv     = (const float*)d_in[2];
  const float* Wk     = (const float*)d_in[3];
  const float* W1     = (const float*)d_in[4];
  const float* b1     = (const float*)d_in[5];
  const float* W2     = (const float*)d_in[6];
  const float* b2     = (const float*)d_in[7];
  const int* g_jkl    = (const int*)d_in[8];
  const int* g_U_ijkl = (const int*)d_in[9];
  const int* g_U_Uijk = (const int*)d_in[10];
  const int* g_U_ujkl = (const int*)d_in[11];

  float* ws    = (float*)d_ws;
  float* tpk   = ws;                               //  8e6 f32 (tpk -> e -> alpha in place)
  unsigned* mu = (unsigned*)(ws + 8000000);        //  2e6
  float* s     = ws + 10000000;                    //  2e6
  float* ker   = ws + 12000000;                    // 16e6
  float* lvl   = ws + 28000000;                    // 36e6  (9 levels of [500k x 8])

  // zero segment accumulators and levels 1..8 (level 0 fully written by GEMM)
  hipMemsetAsync(mu, 0, 4000000 * sizeof(float), stream);
  hipMemsetAsync(lvl + LVL_STRIDE, 0, 8 * LVL_STRIDE * sizeof(float), stream);

  k_gemm128x8<<<N_IJKL / 32, 256, 0, stream>>>(stereo, Wk, tpk);
  k_gemm128x8<<<N_UIJK / 32, 256, 0, stream>>>(prop, Wv, lvl);

  k_segmax<<<(N_IJKL + 255) / 256, 256, 0, stream>>>(tpk, g_jkl, mu);
  k_expsum<<<(N_IJKL + 255) / 256, 256, 0, stream>>>(tpk, g_jkl, mu, s);
  k_div   <<<(N_IJKL + 255) / 256, 256, 0, stream>>>(tpk, g_jkl, s);

  k_gather<<<(N_UIJKL + 255) / 256, 256, 0, stream>>>(tpk, g_U_ijkl, ker);

  for (int t = 0; t < 8; ++t) {
    k_conv<<<(N_UIJKL + 255) / 256, 256, 0, stream>>>(
        ker, g_U_Uijk, g_U_ujkl, lvl + t * LVL_STRIDE, lvl + (t + 1) * LVL_STRIDE);
  }

  k_mlp<<<(N_UIJK + 127) / 128, 128, 0, stream>>>(lvl, prop, W1, b1, W2, b2, (float*)d_out);
}